// Round 11
// baseline (159.144 us; speedup 1.0000x reference)
//
#include <hip/hip_runtime.h>
#include <hip/hip_bf16.h>

// Problem dims
#define Bsz 128
#define Cch 256
#define Him 32
#define Wim 32
#define TD 192
#define NH 4
#define HD 48
#define FF 384
#define NP 64

typedef float f32x4 __attribute__((ext_vector_type(4)));
typedef __bf16 bf16x8 __attribute__((ext_vector_type(8)));
typedef unsigned int u32;
typedef ushort ushort8v __attribute__((ext_vector_type(8)));

#define MFMA(a, b, c) __builtin_amdgcn_mfma_f32_16x16x32_bf16(a, b, c, 0, 0, 0)
#define LGKM0 asm volatile("s_waitcnt lgkmcnt(0)" ::: "memory")
#define SBAR __builtin_amdgcn_s_barrier()

__device__ __forceinline__ ushort f2bf(float f) {
    union { __hip_bfloat16 h; ushort u; } cv;
    cv.h = __float2bfloat16(f);
    return cv.u;
}

// ---- strip-GEMM helpers: A stationary in regs (per phase), B per-lane global ----
__device__ __forceinline__ void loadA6(bf16x8 (&A)[4][6], const ushort* base, int l15, int slot) {
#pragma unroll
    for (int rt = 0; rt < 4; ++rt)
#pragma unroll
        for (int ks = 0; ks < 6; ++ks)
            A[rt][ks] = *reinterpret_cast<const bf16x8*>(base + (rt * 16 + l15) * 200 + ks * 32 + slot * 8);
}

template <int NKS>
__device__ __forceinline__ void loadB(uint4 (&B)[NKS], const ushort* Wg, int row, int Kel, int kofs, int slot) {
#pragma unroll
    for (int ks = 0; ks < NKS; ++ks)
        B[ks] = *reinterpret_cast<const uint4*>(Wg + (size_t)row * Kel + kofs + ks * 32 + slot * 8);
}

template <int NKS>
__device__ __forceinline__ void mfmaStrip(f32x4 (&acc)[4], const bf16x8 (&A)[4][NKS], uint4 (&B)[NKS]) {
#pragma unroll
    for (int ks = 0; ks < NKS; ++ks) {
        bf16x8 bf = *reinterpret_cast<bf16x8*>(&B[ks]);
#pragma unroll
        for (int rt = 0; rt < 4; ++rt)
            acc[rt] = MFMA(A[rt][ks], bf, acc[rt]);
    }
}

// ---------------- prep kernel: wprep (blocks 0..1535) + patch-mean (blocks 1536..2559) ----------------
// wb (ushort): c1[0,49152) c2[49152,98304) qkvT[98304,208896)
//              projT[208896,245760) ffn1T[245760,319488) ffn2T[319488,393216)
__global__ __launch_bounds__(256) void prep_kernel(const float* __restrict__ x,
                                                   const float* __restrict__ c1,
                                                   const float* __restrict__ c2,
                                                   const float* __restrict__ qw,
                                                   const float* __restrict__ pw,
                                                   const float* __restrict__ f1,
                                                   const float* __restrict__ f2,
                                                   ushort* __restrict__ wb,
                                                   ushort* __restrict__ xm) {
    const int bb = blockIdx.x;
    const int tid = threadIdx.x;
    if (bb < 1536) {   // ---- weight convert/transpose ----
        int g = bb * 256 + tid;
        float v;
        if (g < 49152) v = c1[g];
        else if (g < 98304) v = c2[g - 49152];
        else if (g < 208896) { int i = g - 98304;  int n = i / 192, k = i - n * 192; v = qw[k * 576 + n]; }
        else if (g < 245760) { int i = g - 208896; int n = i / 192, k = i - n * 192; v = pw[k * 192 + n]; }
        else if (g < 319488) { int i = g - 245760; int n = i / 192, k = i - n * 192; v = f1[k * 384 + n]; }
        else                 { int i = g - 319488; int n = i / 384, k = i - n * 384; v = f2[k * 192 + n]; }
        wb[g] = f2bf(v);
        return;
    }
    // ---- patch mean: block = (image b, 32-channel group cg) ----
    __shared__ float acc[32][65];
    int pb = bb - 1536;            // 0..1023
    int b = pb >> 3, cg = pb & 7;
    int c = tid >> 3, wq = tid & 7;
    const float* pl = x + ((size_t)(b * Cch + cg * 32 + c) * 1024) + wq * 4;
#pragma unroll 1
    for (int nh = 0; nh < 8; ++nh) {
        const float* p0 = pl + nh * 128;
        float4 v0 = *reinterpret_cast<const float4*>(p0);
        float4 v1 = *reinterpret_cast<const float4*>(p0 + 32);
        float4 v2 = *reinterpret_cast<const float4*>(p0 + 64);
        float4 v3 = *reinterpret_cast<const float4*>(p0 + 96);
        float s = v0.x + v0.y + v0.z + v0.w + v1.x + v1.y + v1.z + v1.w +
                  v2.x + v2.y + v2.z + v2.w + v3.x + v3.y + v3.z + v3.w;
        acc[c][nh * 8 + wq] = s * 0.0625f;
    }
    __syncthreads();
    int p = tid >> 2, c8 = (tid & 3) * 8;
    ushort8v o;
#pragma unroll
    for (int k = 0; k < 8; ++k) o[k] = f2bf(acc[c8 + k][p]);
    *reinterpret_cast<ushort8v*>(xm + ((size_t)(b * 64 + p)) * 256 + cg * 32 + c8) = o;
}

// ---------------- token kernel: one block per image, 8 autonomous waves ----------------
// Each wave owns 16-col output strips for ALL 64 rows; A in regs per phase, B per-lane from global.
// LDS (127488 B):
//  [0,25600)       tln [64][200]  ; P2b0 (attn) ; t2 later
//  [25600,51200)   qb             ; ob ; h0
//  [51200,76800)   kb             ; h1
//  [76800,104448)  vT [192][72]   ; o2 later
//  [104448,122880) P2b1 (attn)
//  [122880,126976) scrP float2[64][8]
//  [126976,127488) scrS float2[64]
__global__ __launch_bounds__(512, 1) void token_kernel(
    const ushort* __restrict__ xm, const ushort* __restrict__ wb,
    const float* __restrict__ qkv_b, const float* __restrict__ proj_b,
    const float* __restrict__ ffn_b1, const float* __restrict__ ffn_b2,
    const float* __restrict__ ln1_g, const float* __restrict__ ln1_b,
    const float* __restrict__ ln2_g, const float* __restrict__ ln2_b,
    const float* __restrict__ alphap, const float* __restrict__ rpb,
    float* __restrict__ tokg, ushort* __restrict__ y) {
    __shared__ __align__(16) char LDS[127488];
    ushort* tln = (ushort*)(LDS);
    ushort* qb  = (ushort*)(LDS + 25600);
    ushort* kb  = (ushort*)(LDS + 51200);
    ushort* vT  = (ushort*)(LDS + 76800);
    float2* scrP = (float2*)(LDS + 122880);
    float2* scrS = (float2*)(LDS + 126976);
    ushort* t2  = tln;
    ushort* obp = qb;
    ushort* h0  = qb;
    ushort* h1  = kb;
    ushort* o2  = vT;

    const int b = blockIdx.x;
    const int tid = threadIdx.x, lane = tid & 63, w = tid >> 6;
    const int l15 = lane & 15, slot = lane >> 4, slot16 = slot * 16;
    const int r = w >> 1, cc = w & 1;          // attention mapping
    const int rowA = r * 16 + l15;
    const int orow = r * 16 + slot * 4;
    const int rbase = slot * 4;
    const float alpha = alphap[0];

    const ushort* c1w   = wb;            // [192][256]
    const ushort* c2w   = wb + 49152;    // [256][192]
    const ushort* qkvT  = wb + 98304;    // [576][192]
    const ushort* projT = wb + 208896;   // [192][192]
    const ushort* f1T   = wb + 245760;   // [384][192]
    const ushort* f2T   = wb + 319488;   // [192][384]

    // 12-strip phases (conv1/proj/ffn2): waves 4-7 duplicate their strip (benign; excluded from LN sums)
    const int sA = w;
    const int sB = (w + 8 < 12) ? (w + 8) : w;
    const bool dup12 = (sB == sA);
    float* tokb = tokg + (size_t)b * 64 * 192;

    // ================ Ph1: conv1 (2 K-half passes, strips sA,sB) ================
    f32x4 tok2[2][4] = {};
#pragma unroll
    for (int kh = 0; kh < 2; ++kh) {
        bf16x8 A[4][4];
#pragma unroll
        for (int rt = 0; rt < 4; ++rt)
#pragma unroll
            for (int ks = 0; ks < 4; ++ks)
                A[rt][ks] = *reinterpret_cast<const bf16x8*>(
                    xm + (size_t)(b * 64 + rt * 16 + l15) * 256 + kh * 128 + ks * 32 + slot * 8);
        uint4 B0[4], B1[4];
        loadB<4>(B0, c1w, sA * 16 + l15, 256, kh * 128, slot);
        loadB<4>(B1, c1w, sB * 16 + l15, 256, kh * 128, slot);
        mfmaStrip<4>(tok2[0], A, B0);
        mfmaStrip<4>(tok2[1], A, B1);
    }
    // ---- LN1 (cross-wave reduce via scrP/scrS) + tokg + tln ----
    {
        float s1v[4][4], s2v[4][4];
#pragma unroll
        for (int rt = 0; rt < 4; ++rt)
#pragma unroll
            for (int j2 = 0; j2 < 4; ++j2) {
                float v0 = tok2[0][rt][j2];
                float v1 = dup12 ? 0.f : tok2[1][rt][j2];
                s1v[rt][j2] = v0 + v1;
                s2v[rt][j2] = v0 * v0 + v1 * v1;
            }
#pragma unroll
        for (int m = 1; m < 16; m <<= 1)
#pragma unroll
            for (int rt = 0; rt < 4; ++rt)
#pragma unroll
                for (int j2 = 0; j2 < 4; ++j2) {
                    s1v[rt][j2] += __shfl_xor(s1v[rt][j2], m);
                    s2v[rt][j2] += __shfl_xor(s2v[rt][j2], m);
                }
        if (l15 == 0)
#pragma unroll
            for (int rt = 0; rt < 4; ++rt)
#pragma unroll
                for (int j2 = 0; j2 < 4; ++j2)
                    scrP[(rt * 16 + rbase + j2) * 8 + w] = make_float2(s1v[rt][j2], s2v[rt][j2]);
        LGKM0; SBAR;
        {
            float sx = 0.f, sy = 0.f;
#pragma unroll
            for (int ww = 0; ww < 8; ++ww) { float2 e = scrP[lane * 8 + ww]; sx += e.x; sy += e.y; }
            float mean = sx * (1.f / 192.f);
            float inv = rsqrtf(sy * (1.f / 192.f) - mean * mean + 1e-5f);
            scrS[lane] = make_float2(mean, inv);
        }
        LGKM0;   // own-wave write->read ordering
        float g0 = ln1_g[sA * 16 + l15], b0 = ln1_b[sA * 16 + l15];
        float g1 = ln1_g[sB * 16 + l15], b1 = ln1_b[sB * 16 + l15];
#pragma unroll
        for (int rt = 0; rt < 4; ++rt)
#pragma unroll
            for (int j2 = 0; j2 < 4; ++j2) {
                int row = rt * 16 + rbase + j2;
                float2 st = scrS[row];
                float v0 = tok2[0][rt][j2], v1 = tok2[1][rt][j2];
                tokb[(size_t)row * 192 + sA * 16 + l15] = v0;
                tokb[(size_t)row * 192 + sB * 16 + l15] = v1;
                tln[row * 200 + sA * 16 + l15] = f2bf((v0 - st.x) * st.y * g0 + b0);
                tln[row * 200 + sB * 16 + l15] = f2bf((v1 - st.x) * st.y * g1 + b1);
            }
        LGKM0; SBAR;
    }

    // ================ Ph2: qkv (strips w,w+8,w+16,w+24,[w+32|pad]) ================
    {
        bf16x8 A[4][6]; loadA6(A, tln, l15, slot);
        int sq[5] = { w, w + 8, w + 16, w + 24, (w + 32 < 36) ? w + 32 : w };
        float bias[5];
#pragma unroll
        for (int i = 0; i < 5; ++i) bias[i] = qkv_b[sq[i] * 16 + l15];

        auto epiQKV = [&](int sv, float bv, f32x4 (&acc)[4]) {
            if (sv < 12) {
                int col = sv * 16 + l15;
#pragma unroll
                for (int rt = 0; rt < 4; ++rt) {
                    int rb2 = rt * 16 + rbase;
#pragma unroll
                    for (int j2 = 0; j2 < 4; ++j2) qb[(rb2 + j2) * 200 + col] = f2bf(acc[rt][j2] + bv);
                }
            } else if (sv < 24) {
                int col = sv * 16 + l15 - 192;
#pragma unroll
                for (int rt = 0; rt < 4; ++rt) {
                    int rb2 = rt * 16 + rbase;
#pragma unroll
                    for (int j2 = 0; j2 < 4; ++j2) kb[(rb2 + j2) * 200 + col] = f2bf(acc[rt][j2] + bv);
                }
            } else {
                int c3 = sv * 16 + l15 - 384;
#pragma unroll
                for (int rt = 0; rt < 4; ++rt) {
                    ushort4 pk;
                    pk.x = f2bf(acc[rt][0] + bv); pk.y = f2bf(acc[rt][1] + bv);
                    pk.z = f2bf(acc[rt][2] + bv); pk.w = f2bf(acc[rt][3] + bv);
                    *reinterpret_cast<ushort4*>(&vT[c3 * 72 + rt * 16 + rbase]) = pk;
                }
            }
        };
        uint4 B0[6], B1[6];
        loadB<6>(B0, qkvT, sq[0] * 16 + l15, 192, 0, slot);
        loadB<6>(B1, qkvT, sq[1] * 16 + l15, 192, 0, slot);
        { f32x4 acc[4] = {}; mfmaStrip<6>(acc, A, B0); loadB<6>(B0, qkvT, sq[2] * 16 + l15, 192, 0, slot); epiQKV(sq[0], bias[0], acc); }
        { f32x4 acc[4] = {}; mfmaStrip<6>(acc, A, B1); loadB<6>(B1, qkvT, sq[3] * 16 + l15, 192, 0, slot); epiQKV(sq[1], bias[1], acc); }
        { f32x4 acc[4] = {}; mfmaStrip<6>(acc, A, B0); loadB<6>(B0, qkvT, sq[4] * 16 + l15, 192, 0, slot); epiQKV(sq[2], bias[2], acc); }
        { f32x4 acc[4] = {}; mfmaStrip<6>(acc, A, B1); epiQKV(sq[3], bias[3], acc); }
        { f32x4 acc[4] = {}; mfmaStrip<6>(acc, A, B0); epiQKV(sq[4], bias[4], acc); }
    }
    LGKM0; SBAR;

    // ================ Ph3: attention (r9 structure, unchanged) ================
    {
        const float scale = 0.14433756729740643f;  // 1/sqrt(48)
        ushort* P2b0 = (ushort*)(LDS + cc * 9216);            // heads 0,1 (tln region, dead)
        ushort* P2b1 = (ushort*)(LDS + 104448 + cc * 9216);   // heads 2,3
#pragma unroll
        for (int p = 0; p < 2; ++p) {
            int h = p * 2 + cc;
            ushort* P2 = p ? P2b1 : P2b0;
            float rb[4][4];
#pragma unroll
            for (int j2 = 0; j2 < 4; ++j2) {
                int qrow = orow + j2, qh = qrow >> 3, qw = qrow & 7;
#pragma unroll
                for (int nf = 0; nf < 4; ++nf) {
                    int krow = l15 + nf * 16;
                    rb[j2][nf] = rpb[((qh - (krow >> 3) + 7) * 15 + (qw - (krow & 7) + 7)) * 4 + h];
                }
            }
            uint4 z = make_uint4(0, 0, 0, 0);
            const char* qrp = (const char*)qb + rowA * 400 + h * 96;
            uint4 qa1 = *(const uint4*)(qrp + slot16);
            uint4 qa2 = (slot < 2) ? *(const uint4*)(qrp + 64 + slot16) : z;
            f32x4 S[4] = {};
#pragma unroll
            for (int nf = 0; nf < 4; ++nf) {
                const char* kp = (const char*)kb + (l15 + nf * 16) * 400 + h * 96;
                uint4 k1 = *(const uint4*)(kp + slot16);
                uint4 k2 = (slot < 2) ? *(const uint4*)(kp + 64 + slot16) : z;
                S[nf] = MFMA(*(bf16x8*)&qa1, *(bf16x8*)&k1, S[nf]);
                S[nf] = MFMA(*(bf16x8*)&qa2, *(bf16x8*)&k2, S[nf]);
            }
#pragma unroll
            for (int j2 = 0; j2 < 4; ++j2) {
                float sv[4]; float mx = -1e30f;
#pragma unroll
                for (int nf = 0; nf < 4; ++nf) { sv[nf] = S[nf][j2] * scale + rb[j2][nf]; mx = fmaxf(mx, sv[nf]); }
#pragma unroll
                for (int m = 1; m < 16; m <<= 1) mx = fmaxf(mx, __shfl_xor(mx, m));
                float sum = 0.f;
#pragma unroll
                for (int nf = 0; nf < 4; ++nf) { sv[nf] = expf(sv[nf] - mx); sum += sv[nf]; }
#pragma unroll
                for (int m = 1; m < 16; m <<= 1) sum += __shfl_xor(sum, m);
                float inv = 1.f / sum;
                int qrow = orow + j2;
#pragma unroll
                for (int nf = 0; nf < 4; ++nf) P2[qrow * 72 + l15 + nf * 16] = f2bf(sv[nf] * inv);
            }
        }
        LGKM0; SBAR;   // all qb/kb reads done before ob (qb region) writes
#pragma unroll
        for (int p = 0; p < 2; ++p) {
            int h = p * 2 + cc;
            ushort* P2 = p ? P2b1 : P2b0;
            f32x4 O[3] = {};
            const char* prow = (const char*)P2 + rowA * 144;
#pragma unroll
            for (int ki = 0; ki < 2; ++ki) {
                bf16x8 pa = *reinterpret_cast<const bf16x8*>(prow + ki * 64 + slot16);
#pragma unroll
                for (int nf = 0; nf < 3; ++nf) {
                    bf16x8 vb = *reinterpret_cast<const bf16x8*>((const char*)vT + (h * 48 + l15 + nf * 16) * 144 + ki * 64 + slot16);
                    O[nf] = MFMA(pa, vb, O[nf]);
                }
            }
#pragma unroll
            for (int nf = 0; nf < 3; ++nf)
#pragma unroll
                for (int j2 = 0; j2 < 4; ++j2)
                    obp[(orow + j2) * 200 + h * 48 + l15 + nf * 16] = f2bf(O[nf][j2]);
        }
        LGKM0; SBAR;   // ob visible
    }

    // ================ Ph4: proj (strips sA,sB) + residual + LN2 ================
    float vv[2][4][4];
    {
        bf16x8 A[4][6]; loadA6(A, obp, l15, slot);
        float pb0 = proj_b[sA * 16 + l15], pb1 = proj_b[sB * 16 + l15];
        uint4 B0[6], B1[6];
        loadB<6>(B0, projT, sA * 16 + l15, 192, 0, slot);
        loadB<6>(B1, projT, sB * 16 + l15, 192, 0, slot);
        f32x4 a0[4] = {}, a1[4] = {};
        mfmaStrip<6>(a0, A, B0);
        mfmaStrip<6>(a1, A, B1);
#pragma unroll
        for (int rt = 0; rt < 4; ++rt)
#pragma unroll
            for (int j2 = 0; j2 < 4; ++j2) {
                int row = rt * 16 + rbase + j2;
                size_t gi0 = (size_t)row * 192 + sA * 16 + l15;
                size_t gi1 = (size_t)row * 192 + sB * 16 + l15;
                float tv0 = tokb[gi0], tv1 = tokb[gi1];
                float v0 = tv0 + alpha * (a0[rt][j2] + pb0);
                float v1 = tv1 + alpha * (a1[rt][j2] + pb1);
                vv[0][rt][j2] = v0; vv[1][rt][j2] = v1;
                tokb[gi0] = v0; tokb[gi1] = v1;
            }
    }
    {
        float s1v[4][4], s2v[4][4];
#pragma unroll
        for (int rt = 0; rt < 4; ++rt)
#pragma unroll
            for (int j2 = 0; j2 < 4; ++j2) {
                float v0 = vv[0][rt][j2];
                float v1 = dup12 ? 0.f : vv[1][rt][j2];
                s1v[rt][j2] = v0 + v1;
                s2v[rt][j2] = v0 * v0 + v1 * v1;
            }
#pragma unroll
        for (int m = 1; m < 16; m <<= 1)
#pragma unroll
            for (int rt = 0; rt < 4; ++rt)
#pragma unroll
                for (int j2 = 0; j2 < 4; ++j2) {
                    s1v[rt][j2] += __shfl_xor(s1v[rt][j2], m);
                    s2v[rt][j2] += __shfl_xor(s2v[rt][j2], m);
                }
        if (l15 == 0)
#pragma unroll
            for (int rt = 0; rt < 4; ++rt)
#pragma unroll
                for (int j2 = 0; j2 < 4; ++j2)
                    scrP[(rt * 16 + rbase + j2) * 8 + w] = make_float2(s1v[rt][j2], s2v[rt][j2]);
        LGKM0; SBAR;
        {
            float sx = 0.f, sy = 0.f;
#pragma unroll
            for (int ww = 0; ww < 8; ++ww) { float2 e = scrP[lane * 8 + ww]; sx += e.x; sy += e.y; }
            float mean = sx * (1.f / 192.f);
            float inv = rsqrtf(sy * (1.f / 192.f) - mean * mean + 1e-5f);
            scrS[lane] = make_float2(mean, inv);
        }
        LGKM0;
        float g0 = ln2_g[sA * 16 + l15], b0 = ln2_b[sA * 16 + l15];
        float g1 = ln2_g[sB * 16 + l15], b1 = ln2_b[sB * 16 + l15];
#pragma unroll
        for (int rt = 0; rt < 4; ++rt)
#pragma unroll
            for (int j2 = 0; j2 < 4; ++j2) {
                int row = rt * 16 + rbase + j2;
                float2 st = scrS[row];
                t2[row * 200 + sA * 16 + l15] = f2bf((vv[0][rt][j2] - st.x) * st.y * g0 + b0);
                t2[row * 200 + sB * 16 + l15] = f2bf((vv[1][rt][j2] - st.x) * st.y * g1 + b1);
            }
        LGKM0; SBAR;
    }

    // ================ Ph5: ffn1 + GELU (strips w,w+8,w+16) ================
    {
        bf16x8 A[4][6]; loadA6(A, t2, l15, slot);
        int sf[3] = { w, w + 8, w + 16 };
        float fb[3];
#pragma unroll
        for (int i = 0; i < 3; ++i) fb[i] = ffn_b1[sf[i] * 16 + l15];
        auto epiF1 = [&](int sv, float bv, f32x4 (&acc)[4]) {
            ushort* hb = (sv < 12) ? h0 : h1;
            int col = ((sv < 12) ? sv * 16 : (sv - 12) * 16) + l15;
#pragma unroll
            for (int rt = 0; rt < 4; ++rt) {
                int rb2 = rt * 16 + rbase;
#pragma unroll
                for (int j2 = 0; j2 < 4; ++j2) {
                    float v = acc[rt][j2] + bv;
                    v = 0.5f * v * (1.f + erff(v * 0.70710678118654752f));
                    hb[(rb2 + j2) * 200 + col] = f2bf(v);
                }
            }
        };
        uint4 B0[6], B1[6];
        loadB<6>(B0, f1T, sf[0] * 16 + l15, 192, 0, slot);
        loadB<6>(B1, f1T, sf[1] * 16 + l15, 192, 0, slot);
        { f32x4 acc[4] = {}; mfmaStrip<6>(acc, A, B0); loadB<6>(B0, f1T, sf[2] * 16 + l15, 192, 0, slot); epiF1(sf[0], fb[0], acc); }
        { f32x4 acc[4] = {}; mfmaStrip<6>(acc, A, B1); epiF1(sf[1], fb[1], acc); }
        { f32x4 acc[4] = {}; mfmaStrip<6>(acc, A, B0); epiF1(sf[2], fb[2], acc); }
    }
    LGKM0; SBAR;

    // ================ Ph6: ffn2 (2 A-passes over h0,h1; strips sA,sB) ================
    f32x4 f2a0[4] = {}, f2a1[4] = {};
    {
        {
            bf16x8 A[4][6]; loadA6(A, h0, l15, slot);
            uint4 B0[6], B1[6];
            loadB<6>(B0, f2T, sA * 16 + l15, 384, 0, slot);
            loadB<6>(B1, f2T, sB * 16 + l15, 384, 0, slot);
            mfmaStrip<6>(f2a0, A, B0);
            mfmaStrip<6>(f2a1, A, B1);
        }
        {
            bf16x8 A[4][6]; loadA6(A, h1, l15, slot);
            uint4 B0[6], B1[6];
            loadB<6>(B0, f2T, sA * 16 + l15, 384, 192, slot);
            loadB<6>(B1, f2T, sB * 16 + l15, 384, 192, slot);
            mfmaStrip<6>(f2a0, A, B0);
            mfmaStrip<6>(f2a1, A, B1);
        }
        float fb0 = ffn_b2[sA * 16 + l15], fb1 = ffn_b2[sB * 16 + l15];
#pragma unroll
        for (int rt = 0; rt < 4; ++rt)
#pragma unroll
            for (int j2 = 0; j2 < 4; ++j2) {
                int row = rt * 16 + rbase + j2;
                float o0 = tokb[(size_t)row * 192 + sA * 16 + l15] + f2a0[rt][j2] + fb0;
                float o1 = tokb[(size_t)row * 192 + sB * 16 + l15] + f2a1[rt][j2] + fb1;
                o2[row * 200 + sA * 16 + l15] = f2bf(o0);
                o2[row * 200 + sB * 16 + l15] = f2bf(o1);
            }
    }
    LGKM0; SBAR;

    // ================ Ph7: conv2 -> y (strips w,w+8 exact) ================
    {
        bf16x8 A[4][6]; loadA6(A, o2, l15, slot);
        int t0 = w, t1 = w + 8;
        uint4 B0[6], B1[6];
        loadB<6>(B0, c2w, t0 * 16 + l15, 192, 0, slot);
        loadB<6>(B1, c2w, t1 * 16 + l15, 192, 0, slot);
        f32x4 a0[4] = {}, a1[4] = {};
        mfmaStrip<6>(a0, A, B0);
        mfmaStrip<6>(a1, A, B1);
        ushort* yb = y + (size_t)b * 64 * 256;
#pragma unroll
        for (int rt = 0; rt < 4; ++rt)
#pragma unroll
            for (int j2 = 0; j2 < 4; ++j2) {
                int row = rt * 16 + rbase + j2;
                yb[(size_t)row * 256 + t0 * 16 + l15] = f2bf(a0[rt][j2]);
                yb[(size_t)row * 256 + t1 * 16 + l15] = f2bf(a1[rt][j2]);
            }
    }
}

// ---------------- final: out = x + broadcast(y bf16), non-temporal out stores ----------------
__global__ __launch_bounds__(256) void final_kernel(const float* __restrict__ x,
                                                    const ushort* __restrict__ y,
                                                    float* __restrict__ out) {
    size_t g = (size_t)blockIdx.x * 256 + threadIdx.x;
    int w4 = g & 7, hh = (g >> 3) & 31, c = (g >> 8) & 255, b = (int)(g >> 16);
    int p = (hh >> 2) * 8 + w4;
    u32 yu = y[((size_t)b * NP + p) * Cch + c];
    union { u32 u; float f; } cv; cv.u = yu << 16;
    float yv = cv.f;
    f32x4 xv = *(reinterpret_cast<const f32x4*>(x) + g);
    f32x4 ov = {xv.x + yv, xv.y + yv, xv.z + yv, xv.w + yv};
    __builtin_nontemporal_store(ov, reinterpret_cast<f32x4*>(out) + g);
}

extern "C" void kernel_launch(void* const* d_in, const int* in_sizes, int n_in,
                              void* d_out, int out_size, void* d_ws, size_t ws_size,
                              hipStream_t stream) {
    const float* x       = (const float*)d_in[0];
    const float* conv1_w = (const float*)d_in[1];
    const float* conv2_w = (const float*)d_in[2];
    const float* qkv_w   = (const float*)d_in[3];
    const float* qkv_b   = (const float*)d_in[4];
    const float* proj_w  = (const float*)d_in[5];
    const float* proj_b  = (const float*)d_in[6];
    const float* ffn_w1  = (const float*)d_in[7];
    const float* ffn_b1  = (const float*)d_in[8];
    const float* ffn_w2  = (const float*)d_in[9];
    const float* ffn_b2  = (const float*)d_in[10];
    const float* ln1_g   = (const float*)d_in[11];
    const float* ln1_b   = (const float*)d_in[12];
    const float* ln2_g   = (const float*)d_in[13];
    const float* ln2_b   = (const float*)d_in[14];
    const float* alpha   = (const float*)d_in[15];
    const float* rpb     = (const float*)d_in[16];
    float* out = (float*)d_out;

    ushort* ybuf = (ushort*)d_ws;                 // 8192*256 bf16
    ushort* xm   = ybuf + 2097152;                // 8192*256 bf16
    ushort* wb   = xm + 2097152;                  // 393216 bf16 weights
    float*  tokg = (float*)(wb + 393216);         // 8192*192 f32

    prep_kernel<<<2560, 256, 0, stream>>>(x, conv1_w, conv2_w, qkv_w, proj_w, ffn_w1, ffn_w2,
                                          wb, xm);
    token_kernel<<<Bsz, 512, 0, stream>>>(xm, wb, qkv_b, proj_b, ffn_b1, ffn_b2,
                                          ln1_g, ln1_b, ln2_g, ln2_b, alpha, rpb, tokg, ybuf);
    final_kernel<<<(Bsz * Cch * Him * Wim) / 1024, 256, 0, stream>>>(x, ybuf, out);
}

// Round 12
// 114.402 us; speedup vs baseline: 1.3911x; 1.3911x over previous
//
#include <hip/hip_runtime.h>
#include <hip/hip_bf16.h>

// Problem dims
#define Bsz 128
#define Cch 256
#define Him 32
#define Wim 32
#define TD 192
#define NH 4
#define HD 48
#define FF 384
#define NP 64

typedef float f32x4 __attribute__((ext_vector_type(4)));
typedef __bf16 bf16x8 __attribute__((ext_vector_type(8)));
typedef unsigned int u32;
typedef ushort ushort8v __attribute__((ext_vector_type(8)));

#define MFMA(a, b, c) __builtin_amdgcn_mfma_f32_16x16x32_bf16(a, b, c, 0, 0, 0)
#define LD8(p) (*reinterpret_cast<const bf16x8*>(p))
#define VM0 asm volatile("s_waitcnt vmcnt(0)" ::: "memory")
#define LGKM0 asm volatile("s_waitcnt lgkmcnt(0)" ::: "memory")
#define SBAR __builtin_amdgcn_s_barrier()

__device__ __forceinline__ ushort f2bf(float f) {
    union { __hip_bfloat16 h; ushort u; } cv;
    cv.h = __float2bfloat16(f);
    return cv.u;
}

__device__ __forceinline__ void gload16(const void* g, void* l) {
    __builtin_amdgcn_global_load_lds((const __attribute__((address_space(1))) u32*)g,
                                     (__attribute__((address_space(3))) u32*)l, 16, 0, 0);
}

// stage a 32-col weight chunk into LDS (1024 threads, single shot).
// LDS logical layout: byte(col,kb) = col*K2B + (kb ^ ((col&7)<<4))
template <int K2B>
__device__ __forceinline__ void stageW(char* lbuf, const char* g0, int colStrB, int tid) {
    constexpr int CHB = 32 * K2B;
    int p = tid * 16;
    if (p < CHB) {
        int col = p / K2B;
        int kb = (p - col * K2B) ^ ((col & 7) << 4);
        gload16(g0 + (size_t)col * colStrB + kb, lbuf + p);
    }
}

// ---------------- prep kernel: wprep (blocks 0..1535) + patch-mean (blocks 1536..2559) ----------------
// wb (ushort): c1[0,49152) c2[49152,98304) qkvT[98304,208896)
//              projT[208896,245760) ffn1T[245760,319488) ffn2T[319488,393216)
__global__ __launch_bounds__(256) void prep_kernel(const float* __restrict__ x,
                                                   const float* __restrict__ c1,
                                                   const float* __restrict__ c2,
                                                   const float* __restrict__ qw,
                                                   const float* __restrict__ pw,
                                                   const float* __restrict__ f1,
                                                   const float* __restrict__ f2,
                                                   ushort* __restrict__ wb,
                                                   ushort* __restrict__ xm) {
    const int bb = blockIdx.x;
    const int tid = threadIdx.x;
    if (bb < 1536) {   // ---- weight convert/transpose ----
        int g = bb * 256 + tid;
        float v;
        if (g < 49152) v = c1[g];
        else if (g < 98304) v = c2[g - 49152];
        else if (g < 208896) { int i = g - 98304;  int n = i / 192, k = i - n * 192; v = qw[k * 576 + n]; }
        else if (g < 245760) { int i = g - 208896; int n = i / 192, k = i - n * 192; v = pw[k * 192 + n]; }
        else if (g < 319488) { int i = g - 245760; int n = i / 192, k = i - n * 192; v = f1[k * 384 + n]; }
        else                 { int i = g - 319488; int n = i / 384, k = i - n * 384; v = f2[k * 192 + n]; }
        wb[g] = f2bf(v);
        return;
    }
    // ---- patch mean: block = (image b, 32-channel group cg) ----
    __shared__ float acc[32][65];
    int pb = bb - 1536;            // 0..1023
    int b = pb >> 3, cg = pb & 7;
    int c = tid >> 3, wq = tid & 7;
    const float* pl = x + ((size_t)(b * Cch + cg * 32 + c) * 1024) + wq * 4;
#pragma unroll 1
    for (int nh = 0; nh < 8; ++nh) {
        const float* p0 = pl + nh * 128;
        float4 v0 = *reinterpret_cast<const float4*>(p0);
        float4 v1 = *reinterpret_cast<const float4*>(p0 + 32);
        float4 v2 = *reinterpret_cast<const float4*>(p0 + 64);
        float4 v3 = *reinterpret_cast<const float4*>(p0 + 96);
        float s = v0.x + v0.y + v0.z + v0.w + v1.x + v1.y + v1.z + v1.w +
                  v2.x + v2.y + v2.z + v2.w + v3.x + v3.y + v3.z + v3.w;
        acc[c][nh * 8 + wq] = s * 0.0625f;
    }
    __syncthreads();
    int p = tid >> 2, c8 = (tid & 3) * 8;
    ushort8v o;
#pragma unroll
    for (int k = 0; k < 8; ++k) o[k] = f2bf(acc[c8 + k][p]);
    *reinterpret_cast<ushort8v*>(xm + ((size_t)(b * 64 + p)) * 256 + cg * 32 + c8) = o;
}

// ---------------- token kernel: one block per image, 16 waves, paired-job staging ----------------
// wave w: r = w&3 (rowgroup), cc = (w>>2)&1, p = w>>3 (job parity), h4 = (w>>2)&3 (attn head)
// per super-iter: VM0; SBAR; stage pair s+1; consume pair s (wave does job 2s+p)
// LDS (160000 B):
//  [0,25600)        tln [64][200]   ; t2 later
//  [25600,51200)    qb              ; ob ; h0
//  [51200,76800)    kb              ; h1
//  [76800,104448)   vT [192][72]    ; o2 later
//  [104448,153600)  stage 4x12288   ; P2[4][64][72] during attn
//  [153600,155648)  scrP float2[64][4]
//  [155648,156160)  scrS float2[64]
//  [156160,158464)  qkv_b f32[576]
//  [158464,160000)  ffn_b1 f32[384]
__global__ __launch_bounds__(1024, 1) void token_kernel(
    const ushort* __restrict__ xm, const ushort* __restrict__ wb,
    const float* __restrict__ qkv_b, const float* __restrict__ proj_b,
    const float* __restrict__ ffn_b1, const float* __restrict__ ffn_b2,
    const float* __restrict__ ln1_g, const float* __restrict__ ln1_b,
    const float* __restrict__ ln2_g, const float* __restrict__ ln2_b,
    const float* __restrict__ alphap, const float* __restrict__ rpb,
    ushort* __restrict__ y) {
    __shared__ __align__(16) char LDS[160000];
    ushort* tln = (ushort*)(LDS);
    ushort* qb  = (ushort*)(LDS + 25600);
    ushort* kb  = (ushort*)(LDS + 51200);
    ushort* vT  = (ushort*)(LDS + 76800);
    char*   SBB = LDS + 104448;
    float2* scrP = (float2*)(LDS + 153600);
    float2* scrS = (float2*)(LDS + 155648);
    float*  qbl  = (float*)(LDS + 156160);
    float*  f1bl = (float*)(LDS + 158464);
    ushort* t2  = tln;
    ushort* obp = qb;
    ushort* h0  = qb;
    ushort* h1  = kb;
    ushort* o2  = vT;
#define SBUF(i) (SBB + (i) * 12288)

    const int b = blockIdx.x;
    const int tid = threadIdx.x, lane = tid & 63, w = tid >> 6;
    const int l15 = lane & 15, slot = lane >> 4, slot16 = slot * 16;
    const int r = w & 3, h4 = (w >> 2) & 3, p = w >> 3;
    const int rowA = r * 16 + l15;
    const int orow = r * 16 + slot * 4;
    const int xp = (l15 & 7) << 4;
    const int colB = ((w >> 2) & 1) * 16 + l15;

    // bias tables -> LDS (read per job via ds_read; no vmem in job loops)
    if (tid < 576) qbl[tid] = qkv_b[tid];
    if (tid < 384) f1bl[tid] = ffn_b1[tid];

    const char* c1g = (const char*)wb;
    const char* qg  = (const char*)(wb + 98304);
    const char* pg  = (const char*)(wb + 208896);
    const char* fg  = (const char*)(wb + 245760);
    const char* f2g = (const char*)(wb + 319488);
    const char* c2g = (const char*)(wb + 49152);

    // conv1 A-frags (from xm, global)
    bf16x8 a1[2][4];
#pragma unroll
    for (int kh = 0; kh < 2; ++kh)
#pragma unroll
        for (int ks = 0; ks < 4; ++ks)
            a1[kh][ks] = LD8(xm + (size_t)(b * 64 + rowA) * 256 + kh * 128 + ks * 32 + slot * 8);

    f32x4 tok[3] = {}, pj[3] = {}, f2a[3] = {};

    // ================ Ph1: conv1 (12 jobs = 6 pairs) ================
    // job j: c=j%6, kh=j/6; addr = c1g + c*16384 + kh*256
    stageW<256>(SBUF(0), c1g + (size_t)0 * 16384, 512, tid);
    stageW<256>(SBUF(1), c1g + (size_t)1 * 16384, 512, tid);
#pragma unroll
    for (int s = 0; s < 6; ++s) {
        VM0; SBAR;
        if (s < 5) {
            int ja = 2 * s + 2, jb = 2 * s + 3;
            stageW<256>(SBUF(ja & 3), c1g + (size_t)(ja % 6) * 16384 + (ja / 6) * 256, 512, tid);
            stageW<256>(SBUF(jb & 3), c1g + (size_t)(jb % 6) * 16384 + (jb / 6) * 256, 512, tid);
        }
        int j = 2 * s + p;
        const char* bp = SBUF(j & 3) + colB * 256;
        const int kh = s / 3, li = s % 3;
#pragma unroll
        for (int ks = 0; ks < 4; ++ks)
            tok[li] = MFMA(a1[kh][ks], LD8(bp + ((ks * 64 + slot16) ^ xp)), tok[li]);
    }
    // qkv pair 0 (bufs 0,1 free: pair4 consumed before s=5's barrier)
    stageW<384>(SBUF(0), qg, 384, tid);
    stageW<384>(SBUF(1), qg + 12288, 384, tid);

    // ---- LN1 ----
    {
        float s1v[4] = {}, s2v[4] = {};
#pragma unroll
        for (int i = 0; i < 3; ++i)
#pragma unroll
            for (int j2 = 0; j2 < 4; ++j2) { float v = tok[i][j2]; s1v[j2] += v; s2v[j2] += v * v; }
#pragma unroll
        for (int m = 1; m < 16; m <<= 1)
#pragma unroll
            for (int j2 = 0; j2 < 4; ++j2) { s1v[j2] += __shfl_xor(s1v[j2], m); s2v[j2] += __shfl_xor(s2v[j2], m); }
        if (l15 == 0)
#pragma unroll
            for (int j2 = 0; j2 < 4; ++j2) scrP[(orow + j2) * 4 + h4] = make_float2(s1v[j2], s2v[j2]);
        LGKM0; SBAR;
        {
            float sx = 0.f, sy = 0.f;
#pragma unroll
            for (int g2 = 0; g2 < 4; ++g2) { float2 e = scrP[lane * 4 + g2]; sx += e.x; sy += e.y; }
            float mean = sx * (1.f / 192.f);
            float inv = rsqrtf(sy * (1.f / 192.f) - mean * mean + 1e-5f);
            scrS[lane] = make_float2(mean, inv);
        }
        LGKM0;
#pragma unroll
        for (int i = 0; i < 3; ++i) {
            int col = (2 * i + p) * 32 + colB;
            float gg = ln1_g[col], bb2 = ln1_b[col];
#pragma unroll
            for (int j2 = 0; j2 < 4; ++j2) {
                int row = orow + j2;
                float2 st = scrS[row];
                tln[row * 200 + col] = f2bf((tok[i][j2] - st.x) * st.y * gg + bb2);
            }
        }
        LGKM0; SBAR;
    }

    // ================ Ph2: qkv (18 jobs = 9 pairs) ================
    {
        bf16x8 aT[6];
#pragma unroll
        for (int ks = 0; ks < 6; ++ks) aT[ks] = LD8((const char*)tln + rowA * 400 + ks * 64 + slot16);
#pragma unroll
        for (int s = 0; s < 9; ++s) {
            VM0; SBAR;
            if (s < 8) {
                stageW<384>(SBUF((2 * s + 2) & 3), qg + (size_t)(2 * s + 2) * 12288, 384, tid);
                stageW<384>(SBUF((2 * s + 3) & 3), qg + (size_t)(2 * s + 3) * 12288, 384, tid);
            }
            int j = 2 * s + p;
            const char* bp = SBUF(j & 3) + colB * 384;
            f32x4 acc = f32x4{0, 0, 0, 0};
#pragma unroll
            for (int ks = 0; ks < 6; ++ks)
                acc = MFMA(aT[ks], LD8(bp + ((ks * 64 + slot16) ^ xp)), acc);
            const int sel = s / 3;
            int colj = (j - sel * 6) * 32 + colB;
            float bias = qbl[sel * 192 + colj];
            if (sel == 0) {
#pragma unroll
                for (int j2 = 0; j2 < 4; ++j2) qb[(orow + j2) * 200 + colj] = f2bf(acc[j2] + bias);
            } else if (sel == 1) {
#pragma unroll
                for (int j2 = 0; j2 < 4; ++j2) kb[(orow + j2) * 200 + colj] = f2bf(acc[j2] + bias);
            } else {
                ushort4 pk;
                pk.x = f2bf(acc[0] + bias); pk.y = f2bf(acc[1] + bias);
                pk.z = f2bf(acc[2] + bias); pk.w = f2bf(acc[3] + bias);
                *reinterpret_cast<ushort4*>(&vT[colj * 72 + orow]) = pk;  // transposed
            }
        }
    }
    LGKM0; SBAR;

    // ================ Ph3: attention, single pass (wave = rowgroup r x head h4) ================
    {
        const float scale = 0.14433756729740643f;  // 1/sqrt(48)
        ushort* P2 = (ushort*)(LDS + 104448 + h4 * 9216);
        float rb[4][4];
#pragma unroll
        for (int j2 = 0; j2 < 4; ++j2) {
            int qrow = orow + j2, qh = qrow >> 3, qw = qrow & 7;
#pragma unroll
            for (int nf = 0; nf < 4; ++nf) {
                int krow = l15 + nf * 16;
                rb[j2][nf] = rpb[((qh - (krow >> 3) + 7) * 15 + (qw - (krow & 7) + 7)) * 4 + h4];
            }
        }
        uint4 z = make_uint4(0, 0, 0, 0);
        const char* qrp = (const char*)qb + rowA * 400 + h4 * 96;
        uint4 qa1 = *(const uint4*)(qrp + slot16);
        uint4 qa2 = (slot < 2) ? *(const uint4*)(qrp + 64 + slot16) : z;
        f32x4 S[4] = {};
#pragma unroll
        for (int nf = 0; nf < 4; ++nf) {
            const char* kp = (const char*)kb + (l15 + nf * 16) * 400 + h4 * 96;
            uint4 k1 = *(const uint4*)(kp + slot16);
            uint4 k2 = (slot < 2) ? *(const uint4*)(kp + 64 + slot16) : z;
            S[nf] = MFMA(*(bf16x8*)&qa1, *(bf16x8*)&k1, S[nf]);
            S[nf] = MFMA(*(bf16x8*)&qa2, *(bf16x8*)&k2, S[nf]);
        }
#pragma unroll
        for (int j2 = 0; j2 < 4; ++j2) {
            float sv[4]; float mx = -1e30f;
#pragma unroll
            for (int nf = 0; nf < 4; ++nf) { sv[nf] = S[nf][j2] * scale + rb[j2][nf]; mx = fmaxf(mx, sv[nf]); }
#pragma unroll
            for (int m = 1; m < 16; m <<= 1) mx = fmaxf(mx, __shfl_xor(mx, m));
            float sum = 0.f;
#pragma unroll
            for (int nf = 0; nf < 4; ++nf) { sv[nf] = expf(sv[nf] - mx); sum += sv[nf]; }
#pragma unroll
            for (int m = 1; m < 16; m <<= 1) sum += __shfl_xor(sum, m);
            float inv = 1.f / sum;
            int qrow = orow + j2;
#pragma unroll
            for (int nf = 0; nf < 4; ++nf) P2[qrow * 72 + l15 + nf * 16] = f2bf(sv[nf] * inv);
        }
        LGKM0; SBAR;   // all qb/kb reads done before ob (qb region) writes
        f32x4 O[3] = {};
        const char* prow = (const char*)P2 + rowA * 144;
#pragma unroll
        for (int ki = 0; ki < 2; ++ki) {
            bf16x8 pa = LD8(prow + ki * 64 + slot16);
#pragma unroll
            for (int nf = 0; nf < 3; ++nf) {
                bf16x8 vb = LD8((const char*)vT + (h4 * 48 + l15 + nf * 16) * 144 + ki * 64 + slot16);
                O[nf] = MFMA(pa, vb, O[nf]);
            }
        }
#pragma unroll
        for (int nf = 0; nf < 3; ++nf)
#pragma unroll
            for (int j2 = 0; j2 < 4; ++j2)
                obp[(orow + j2) * 200 + h4 * 48 + l15 + nf * 16] = f2bf(O[nf][j2]);
        LGKM0; SBAR;   // ob visible; P2 (stage region) dead -> reusable
    }
    stageW<384>(SBUF(0), pg, 384, tid);
    stageW<384>(SBUF(1), pg + 12288, 384, tid);

    // ================ Ph4: proj (6 jobs = 3 pairs) ================
    {
        bf16x8 aO[6];
#pragma unroll
        for (int ks = 0; ks < 6; ++ks) aO[ks] = LD8((const char*)obp + rowA * 400 + ks * 64 + slot16);
#pragma unroll
        for (int s = 0; s < 3; ++s) {
            VM0; SBAR;
            if (s < 2) {
                stageW<384>(SBUF((2 * s + 2) & 3), pg + (size_t)(2 * s + 2) * 12288, 384, tid);
                stageW<384>(SBUF((2 * s + 3) & 3), pg + (size_t)(2 * s + 3) * 12288, 384, tid);
            }
            int j = 2 * s + p;
            const char* bp = SBUF(j & 3) + colB * 384;
            f32x4 acc = f32x4{0, 0, 0, 0};
#pragma unroll
            for (int ks = 0; ks < 6; ++ks)
                acc = MFMA(aO[ks], LD8(bp + ((ks * 64 + slot16) ^ xp)), acc);
            pj[s] = acc;
        }
    }
    // ---- residual + LN2 ----
    {
        const float alpha = alphap[0];
        float s1v[4] = {}, s2v[4] = {};
#pragma unroll
        for (int i = 0; i < 3; ++i) {
            int col = (2 * i + p) * 32 + colB;
            float pb = proj_b[col];
#pragma unroll
            for (int j2 = 0; j2 < 4; ++j2) {
                float v = tok[i][j2] + alpha * (pj[i][j2] + pb);
                pj[i][j2] = v;
                s1v[j2] += v; s2v[j2] += v * v;
            }
        }
#pragma unroll
        for (int m = 1; m < 16; m <<= 1)
#pragma unroll
            for (int j2 = 0; j2 < 4; ++j2) { s1v[j2] += __shfl_xor(s1v[j2], m); s2v[j2] += __shfl_xor(s2v[j2], m); }
        if (l15 == 0)
#pragma unroll
            for (int j2 = 0; j2 < 4; ++j2) scrP[(orow + j2) * 4 + h4] = make_float2(s1v[j2], s2v[j2]);
        LGKM0; SBAR;   // also: all waves done consuming proj pair 2 (bufs 0,1)
        stageW<384>(SBUF(0), fg, 384, tid);
        stageW<384>(SBUF(1), fg + 12288, 384, tid);
        {
            float sx = 0.f, sy = 0.f;
#pragma unroll
            for (int g2 = 0; g2 < 4; ++g2) { float2 e = scrP[lane * 4 + g2]; sx += e.x; sy += e.y; }
            float mean = sx * (1.f / 192.f);
            float inv = rsqrtf(sy * (1.f / 192.f) - mean * mean + 1e-5f);
            scrS[lane] = make_float2(mean, inv);
        }
        LGKM0;
#pragma unroll
        for (int i = 0; i < 3; ++i) {
            int col = (2 * i + p) * 32 + colB;
            float gg = ln2_g[col], bb2 = ln2_b[col];
#pragma unroll
            for (int j2 = 0; j2 < 4; ++j2) {
                int row = orow + j2;
                float2 st = scrS[row];
                t2[row * 200 + col] = f2bf((pj[i][j2] - st.x) * st.y * gg + bb2);
            }
        }
        LGKM0; SBAR;
    }

    // ================ Ph5: ffn1 + GELU (12 jobs = 6 pairs) ================
    {
        bf16x8 aT2[6];
#pragma unroll
        for (int ks = 0; ks < 6; ++ks) aT2[ks] = LD8((const char*)t2 + rowA * 400 + ks * 64 + slot16);
#pragma unroll
        for (int s = 0; s < 6; ++s) {
            VM0; SBAR;
            if (s < 5) {
                stageW<384>(SBUF((2 * s + 2) & 3), fg + (size_t)(2 * s + 2) * 12288, 384, tid);
                stageW<384>(SBUF((2 * s + 3) & 3), fg + (size_t)(2 * s + 3) * 12288, 384, tid);
            }
            int j = 2 * s + p;
            const char* bp = SBUF(j & 3) + colB * 384;
            f32x4 acc = f32x4{0, 0, 0, 0};
#pragma unroll
            for (int ks = 0; ks < 6; ++ks)
                acc = MFMA(aT2[ks], LD8(bp + ((ks * 64 + slot16) ^ xp)), acc);
            ushort* hb = (s < 3) ? h0 : h1;
            int lcol = (j - (s < 3 ? 0 : 6)) * 32 + colB;
            float bias = f1bl[j * 32 + colB];
#pragma unroll
            for (int j2 = 0; j2 < 4; ++j2) {
                float v = acc[j2] + bias;
                v = 0.5f * v * (1.f + erff(v * 0.70710678118654752f));
                hb[(orow + j2) * 200 + lcol] = f2bf(v);
            }
        }
    }
    LGKM0; SBAR;
    // ffn2 pair 0: job j: c=j%6, kh=j/6; addr = f2g + c*24576 + kh*384 (colStr 768)
    stageW<384>(SBUF(0), f2g, 768, tid);
    stageW<384>(SBUF(1), f2g + 24576, 768, tid);

    // ================ Ph6: ffn2 (12 jobs = 6 pairs) ================
    {
        bf16x8 ah0[6], ah1[6];
#pragma unroll
        for (int ks = 0; ks < 6; ++ks) {
            ah0[ks] = LD8((const char*)h0 + rowA * 400 + ks * 64 + slot16);
            ah1[ks] = LD8((const char*)h1 + rowA * 400 + ks * 64 + slot16);
        }
#pragma unroll
        for (int s = 0; s < 6; ++s) {
            VM0; SBAR;
            if (s < 5) {
                int ja = 2 * s + 2, jb = 2 * s + 3;
                stageW<384>(SBUF(ja & 3), f2g + (size_t)(ja % 6) * 24576 + (ja / 6) * 384, 768, tid);
                stageW<384>(SBUF(jb & 3), f2g + (size_t)(jb % 6) * 24576 + (jb / 6) * 384, 768, tid);
            }
            int j = 2 * s + p;
            const char* bp = SBUF(j & 3) + colB * 384;
            const int kh = s / 3, li = s % 3;
#pragma unroll
            for (int ks = 0; ks < 6; ++ks) {
                bf16x8 af = kh ? ah1[ks] : ah0[ks];
                f2a[li] = MFMA(af, LD8(bp + ((ks * 64 + slot16) ^ xp)), f2a[li]);
            }
        }
    }
    // conv2 pair 0 (bufs 0,1 free: ffn2 pair 4 consumed before s=5's barrier)
    stageW<384>(SBUF(0), c2g, 384, tid);
    stageW<384>(SBUF(1), c2g + 12288, 384, tid);
    // o2 epilogue
#pragma unroll
    for (int i = 0; i < 3; ++i) {
        int col = (2 * i + p) * 32 + colB;
        float fb = ffn_b2[col];
#pragma unroll
        for (int j2 = 0; j2 < 4; ++j2)
            o2[(orow + j2) * 200 + col] = f2bf(pj[i][j2] + f2a[i][j2] + fb);
    }
    LGKM0; SBAR;

    // ================ Ph7: conv2 -> y bf16 (8 jobs = 4 pairs) ================
    {
        bf16x8 aO2[6];
#pragma unroll
        for (int ks = 0; ks < 6; ++ks) aO2[ks] = LD8((const char*)o2 + rowA * 400 + ks * 64 + slot16);
        ushort* yb = y + (size_t)b * 64 * 256;
#pragma unroll
        for (int s = 0; s < 4; ++s) {
            VM0; SBAR;
            if (s < 3) {
                stageW<384>(SBUF((2 * s + 2) & 3), c2g + (size_t)(2 * s + 2) * 12288, 384, tid);
                stageW<384>(SBUF((2 * s + 3) & 3), c2g + (size_t)(2 * s + 3) * 12288, 384, tid);
            }
            int j = 2 * s + p;
            const char* bp = SBUF(j & 3) + colB * 384;
            f32x4 acc = f32x4{0, 0, 0, 0};
#pragma unroll
            for (int ks = 0; ks < 6; ++ks)
                acc = MFMA(aO2[ks], LD8(bp + ((ks * 64 + slot16) ^ xp)), acc);
            int col = j * 32 + colB;
#pragma unroll
            for (int j2 = 0; j2 < 4; ++j2)
                yb[(size_t)(orow + j2) * 256 + col] = f2bf(acc[j2]);
        }
    }
#undef SBUF
}

// ---------------- final: out = x + broadcast(y bf16), non-temporal out stores ----------------
__global__ __launch_bounds__(256) void final_kernel(const float* __restrict__ x,
                                                    const ushort* __restrict__ y,
                                                    float* __restrict__ out) {
    size_t g = (size_t)blockIdx.x * 256 + threadIdx.x;
    int w4 = g & 7, hh = (g >> 3) & 31, c = (g >> 8) & 255, b = (int)(g >> 16);
    int p = (hh >> 2) * 8 + w4;
    u32 yu = y[((size_t)b * NP + p) * Cch + c];
    union { u32 u; float f; } cv; cv.u = yu << 16;
    float yv = cv.f;
    f32x4 xv = *(reinterpret_cast<const f32x4*>(x) + g);
    f32x4 ov = {xv.x + yv, xv.y + yv, xv.z + yv, xv.w + yv};
    __builtin_nontemporal_store(ov, reinterpret_cast<f32x4*>(out) + g);
}

extern "C" void kernel_launch(void* const* d_in, const int* in_sizes, int n_in,
                              void* d_out, int out_size, void* d_ws, size_t ws_size,
                              hipStream_t stream) {
    const float* x       = (const float*)d_in[0];
    const float* conv1_w = (const float*)d_in[1];
    const float* conv2_w = (const float*)d_in[2];
    const float* qkv_w   = (const float*)d_in[3];
    const float* qkv_b   = (const float*)d_in[4];
    const float* proj_w  = (const float*)d_in[5];
    const float* proj_b  = (const float*)d_in[6];
    const float* ffn_w1  = (const float*)d_in[7];
    const float* ffn_b1  = (const float*)d_in[8];
    const float* ffn_w2  = (const float*)d_in[9];
    const float* ffn_b2  = (const float*)d_in[10];
    const float* ln1_g   = (const float*)d_in[11];
    const float* ln1_b   = (const float*)d_in[12];
    const float* ln2_g   = (const float*)d_in[13];
    const float* ln2_b   = (const float*)d_in[14];
    const float* alpha   = (const float*)d_in[15];
    const float* rpb     = (const float*)d_in[16];
    float* out = (float*)d_out;

    ushort* ybuf = (ushort*)d_ws;                 // 8192*256 bf16
    ushort* xm   = ybuf + 2097152;                // 8192*256 bf16
    ushort* wb   = xm + 2097152;                  // 393216 bf16 weights

    prep_kernel<<<2560, 256, 0, stream>>>(x, conv1_w, conv2_w, qkv_w, proj_w, ffn_w1, ffn_w2,
                                          wb, xm);
    token_kernel<<<Bsz, 1024, 0, stream>>>(xm, wb, qkv_b, proj_b, ffn_b1, ffn_b2,
                                           ln1_g, ln1_b, ln2_g, ln2_b, alpha, rpb, ybuf);
    final_kernel<<<(Bsz * Cch * Him * Wim) / 1024, 256, 0, stream>>>(x, ybuf, out);
}